// Round 10
// baseline (162.294 us; speedup 1.0000x reference)
//
#include <hip/hip_runtime.h>
#include <math.h>

typedef _Float16 f16x2 __attribute__((ext_vector_type(2)));
typedef float    f32x2 __attribute__((ext_vector_type(2)));

#define GT_N 1024
#define NPAIR 280                // 128 (W2) + 128 (W3) + 24 (Wh) f16x2 pairs
#define PPT 2

// ---------------- featuremap repack: (4,H,W) -> (H,W,4) ----------------
__global__ void repack_fm_kernel(const float* __restrict__ fm,
                                 float4* __restrict__ out, int HW) {
    int idx = blockIdx.x * blockDim.x + threadIdx.x;
    if (idx >= HW) return;
    float4 v;
    v.x = fm[idx];
    v.y = fm[HW + idx];
    v.z = fm[2 * HW + idx];
    v.w = fm[3 * HW + idx];
    out[idx] = v;
}

// ------- GELU slope/intercept table: g(v) ~= s[i]*v + c[i], 1024 buckets on [-5,5] -------
// Built in f64 for exactness. Out-of-range v self-handles: bucket 0 line ~ 0*v+0,
// bucket 1023 line ~ 1.0*v - 1e-6, so no select is needed at eval time.
__global__ void build_gelu_table_kernel(float2* __restrict__ tbl) {
    int i = blockIdx.x * blockDim.x + threadIdx.x;
    if (i >= GT_N) return;
    double d  = 10.0 / 1023.0;
    double v0 = -5.0 + (double)i * d;
    double v1 = v0 + d;
    double g0 = 0.5 * v0 * (1.0 + erf(v0 * 0.70710678118654752440));
    double g1 = 0.5 * v1 * (1.0 + erf(v1 * 0.70710678118654752440));
    double s  = (g1 - g0) / d;
    double c  = g0 - s * v0;
    float2 e; e.x = (float)s; e.y = (float)c;
    tbl[i] = e;
}

// ---------------- pack W2/W3/Wh rows into f16 pairs (RNE) ----------------
__global__ void pack_weights_kernel(const float* __restrict__ W2,
                                    const float* __restrict__ W3,
                                    const float* __restrict__ Wh,
                                    unsigned* __restrict__ wp) {
    int t = blockIdx.x * blockDim.x + threadIdx.x;
    if (t >= NPAIR) return;
    float a, b;
    if (t < 128)      {              a = W2[2 * t];  b = W2[2 * t + 1]; }
    else if (t < 256) { int u = t - 128; a = W3[2 * u]; b = W3[2 * u + 1]; }
    else              { int u = t - 256; a = Wh[2 * u]; b = Wh[2 * u + 1]; }
    union { f16x2 h; unsigned u; } cv;
    cv.h.x = (_Float16)a; cv.h.y = (_Float16)b;
    wp[t] = cv.u;
}

// Fallback exact GELU (A&S 7.1.26 erfc), branchless — only for the no-ws path.
__device__ __forceinline__ float gelu_as(float v) {
    float z = fabsf(v) * 0.70710678118654752440f;
    float t = __builtin_amdgcn_rcpf(fmaf(0.3275911f, z, 1.0f));
    float e = __expf(-z * z);
    float p = fmaf(1.061405429f, t, -1.453152027f);
    p = fmaf(p, t, 1.421413741f);
    p = fmaf(p, t, -0.284496736f);
    p = fmaf(p, t, 0.254829592f);
    p = p * t;
    float he = 0.5f * p * e;
    float phi = (v >= 0.0f) ? (1.0f - he) : he;
    return v * phi;
}

// 5 VALU + 1 LDS: med3, fma(index), cvt_i32, lshl(in addressing), ds_read_b64, fma(eval)
__device__ __forceinline__ float gelu_lin(float v, const float2* __restrict__ gt) {
    float u = __builtin_amdgcn_fmed3f(v, -5.0f, 5.0f);
    float t = fmaf(u, 102.3f, 511.5f);      // [-5,5] -> [0,1023]
    int idx = (int)t;                       // trunc; t >= -2e-5 so safe
    float2 sc = gt[idx];
    return fmaf(v, sc.x, sc.y);             // UNCLAMPED v: edge lines extrapolate correctly
}

__device__ __forceinline__ f16x2 pk(float a, float b) {   // RNE pack
    f16x2 r; r.x = (_Float16)a; r.y = (_Float16)b; return r;
}

// ---------- bilinear sample + input-feature build (shared) ----------
template <bool REPACKED>
__device__ __forceinline__ void build_inp(
    float xa, float xb, float xc,
    const float* __restrict__ fm, const float4* __restrict__ fmr,
    int H, int W, float* inp)
{
    float gx = xa * 2.0f - 1.0f;
    float gy = xb * 2.0f - 1.0f;
    float ix = ((gx + 1.0f) * (float)W - 1.0f) * 0.5f;
    float iy = ((gy + 1.0f) * (float)H - 1.0f) * 0.5f;
    ix = fminf(fmaxf(ix, 0.0f), (float)(W - 1));
    iy = fminf(fmaxf(iy, 0.0f), (float)(H - 1));
    float x0f = floorf(ix), y0f = floorf(iy);
    float wx = ix - x0f, wy = iy - y0f;
    int x0 = (int)x0f, y0 = (int)y0f;
    int x1 = x0 + 1; if (x1 > W - 1) x1 = W - 1;
    int y1 = y0 + 1; if (y1 > H - 1) y1 = H - 1;

    float4 f00, f01, f10, f11;
    if (REPACKED) {
        f00 = fmr[y0 * W + x0];
        f01 = fmr[y0 * W + x1];
        f10 = fmr[y1 * W + x0];
        f11 = fmr[y1 * W + x1];
    } else {
        int HW = H * W;
        const float* c0 = fm;
        const float* c1 = fm + HW;
        const float* c2 = fm + 2 * HW;
        const float* c3 = fm + 3 * HW;
        int i00 = y0 * W + x0, i01 = y0 * W + x1;
        int i10 = y1 * W + x0, i11 = y1 * W + x1;
        f00 = make_float4(c0[i00], c1[i00], c2[i00], c3[i00]);
        f01 = make_float4(c0[i01], c1[i01], c2[i01], c3[i01]);
        f10 = make_float4(c0[i10], c1[i10], c2[i10], c3[i10]);
        f11 = make_float4(c0[i11], c1[i11], c2[i11], c3[i11]);
    }
    float omwx = 1.0f - wx, omwy = 1.0f - wy;
    float tx = f00.x * omwx + f01.x * wx, bx = f10.x * omwx + f11.x * wx;
    float ty = f00.y * omwx + f01.y * wx, by = f10.y * omwx + f11.y * wx;
    float tz = f00.z * omwx + f01.z * wx, bz = f10.z * omwx + f11.z * wx;
    float tw = f00.w * omwx + f01.w * wx, bw = f10.w * omwx + f11.w * wx;

    inp[0] = xa;
    inp[1] = xb;
    inp[2] = xc;
    inp[3] = tx * omwy + bx * wy;
    inp[4] = ty * omwy + by * wy;
    inp[5] = tz * omwy + bz * wy;
    inp[6] = tw * omwy + bw * wy;
    inp[7] = __expf(xc) - 1.0f;
}

// ---------------- FAST kernel: PPT=2, L1 fp32, L2/L3/head via v_dot2_f32_f16 ----------------
template <bool REPACKED>
__global__ __launch_bounds__(256) void fused_mlp_fast_kernel(
    const float* __restrict__ x,
    const float* __restrict__ fm,
    const float4* __restrict__ fmr,
    const float2* __restrict__ gtab,
    const f16x2* __restrict__ wpk,   // packed: W2[0,128) W3[128,256) Wh[256,280)
    const float* __restrict__ W1, const float* __restrict__ b1,
    const float* __restrict__ b2, const float* __restrict__ b3,
    const float* __restrict__ bh,
    float* __restrict__ out, int B, int H, int W)
{
    __shared__ float2 gt[GT_N];
    {
        int t = threadIdx.x;
        #pragma unroll
        for (int k = 0; k < GT_N / 256; ++k)
            gt[t + 256 * k] = gtab[t + 256 * k];
        __syncthreads();
    }

    int tid = blockIdx.x * blockDim.x + threadIdx.x;
    long base = (long)tid * PPT;
    if (base >= B) return;
    bool full = (base + PPT <= B);

    // ---- load x: 2 points = 6 floats = 3x f32x2 (contiguous, streaming) ----
    float xv[PPT][3];
    if (full) {
        const f32x2* xp = (const f32x2*)(x + base * 3);
        f32x2 a = __builtin_nontemporal_load(xp + 0);
        f32x2 b = __builtin_nontemporal_load(xp + 1);
        f32x2 c = __builtin_nontemporal_load(xp + 2);
        xv[0][0] = a.x; xv[0][1] = a.y; xv[0][2] = b.x;
        xv[1][0] = b.y; xv[1][1] = c.x; xv[1][2] = c.y;
    } else {
        #pragma unroll
        for (int p = 0; p < PPT; ++p) {
            long i = base + p; if (i > B - 1) i = B - 1;
            xv[p][0] = x[i * 3 + 0];
            xv[p][1] = x[i * 3 + 1];
            xv[p][2] = x[i * 3 + 2];
        }
    }

    float o[PPT][3];
    #pragma unroll
    for (int p = 0; p < PPT; ++p) {
        float inp[8];
        build_inp<REPACKED>(xv[p][0], xv[p][1], xv[p][2], fm, fmr, H, W, inp);

        // ---- layer 1: 8 -> 16, fp32 FMA (weights scalarized), gelu -> f16 pairs ----
        f16x2 hp[8];
        #pragma unroll
        for (int e = 0; e < 8; ++e) {
            float a0 = b1[2 * e], a1 = b1[2 * e + 1];
            #pragma unroll
            for (int k = 0; k < 8; ++k) {
                a0 = fmaf(W1[(2 * e) * 8 + k], inp[k], a0);
                a1 = fmaf(W1[(2 * e + 1) * 8 + k], inp[k], a1);
            }
            hp[e] = pk(gelu_lin(a0, gt), gelu_lin(a1, gt));
        }

        // ---- layer 2: 16 -> 16 via dot2 ----
        f16x2 hq[8];
        #pragma unroll
        for (int e = 0; e < 8; ++e) {
            float a0 = b2[2 * e], a1 = b2[2 * e + 1];
            #pragma unroll
            for (int k = 0; k < 8; ++k) {
                a0 = __builtin_amdgcn_fdot2(hp[k], wpk[(2 * e) * 8 + k], a0, false);
                a1 = __builtin_amdgcn_fdot2(hp[k], wpk[(2 * e + 1) * 8 + k], a1, false);
            }
            hq[e] = pk(gelu_lin(a0, gt), gelu_lin(a1, gt));
        }

        // ---- layer 3: 16 -> 16 via dot2 ----
        #pragma unroll
        for (int e = 0; e < 8; ++e) {
            float a0 = b3[2 * e], a1 = b3[2 * e + 1];
            #pragma unroll
            for (int k = 0; k < 8; ++k) {
                a0 = __builtin_amdgcn_fdot2(hq[k], wpk[128 + (2 * e) * 8 + k], a0, false);
                a1 = __builtin_amdgcn_fdot2(hq[k], wpk[128 + (2 * e + 1) * 8 + k], a1, false);
            }
            hp[e] = pk(gelu_lin(a0, gt), gelu_lin(a1, gt));
        }

        // ---- head: 16 -> 3 via dot2 ----
        float o0 = bh[0], o1 = bh[1], o2 = bh[2];
        #pragma unroll
        for (int k = 0; k < 8; ++k) {
            o0 = __builtin_amdgcn_fdot2(hp[k], wpk[256 + 0 * 8 + k], o0, false);
            o1 = __builtin_amdgcn_fdot2(hp[k], wpk[256 + 1 * 8 + k], o1, false);
            o2 = __builtin_amdgcn_fdot2(hp[k], wpk[256 + 2 * 8 + k], o2, false);
        }
        o[p][0] = o0; o[p][1] = o1; o[p][2] = o2;
    }

    // ---- store: 6 floats = 3x f32x2 (streaming) ----
    if (full) {
        f32x2* op = (f32x2*)(out + base * 3);
        f32x2 s0; s0.x = o[0][0]; s0.y = o[0][1];
        f32x2 s1; s1.x = o[0][2]; s1.y = o[1][0];
        f32x2 s2; s2.x = o[1][1]; s2.y = o[1][2];
        __builtin_nontemporal_store(s0, op + 0);
        __builtin_nontemporal_store(s1, op + 1);
        __builtin_nontemporal_store(s2, op + 2);
    } else {
        #pragma unroll
        for (int p = 0; p < PPT; ++p) {
            long i = base + p;
            if (i < B) {
                out[i * 3 + 0] = o[p][0];
                out[i * 3 + 1] = o[p][1];
                out[i * 3 + 2] = o[p][2];
            }
        }
    }
}

// ---------------- legacy fp32 kernel (fallback if ws too small) ----------------
template <bool REPACKED>
__global__ __launch_bounds__(256) void fused_mlp_kernel(
    const float* __restrict__ x,
    const float* __restrict__ fm,
    const float4* __restrict__ fmr,
    const float* __restrict__ W1, const float* __restrict__ b1,
    const float* __restrict__ W2, const float* __restrict__ b2,
    const float* __restrict__ W3, const float* __restrict__ b3,
    const float* __restrict__ Wh, const float* __restrict__ bh,
    float* __restrict__ out, int B, int H, int W)
{
    int i = blockIdx.x * blockDim.x + threadIdx.x;
    if (i >= B) return;

    const float* xp = x + (size_t)i * 3;
    float xa = __builtin_nontemporal_load(xp + 0);
    float xb = __builtin_nontemporal_load(xp + 1);
    float xc = __builtin_nontemporal_load(xp + 2);

    float inp[8];
    build_inp<REPACKED>(xa, xb, xc, fm, fmr, H, W, inp);

    float h1[16];
    #pragma unroll
    for (int j = 0; j < 16; ++j) {
        float acc = b1[j];
        #pragma unroll
        for (int k = 0; k < 8; ++k) acc = fmaf(W1[j * 8 + k], inp[k], acc);
        h1[j] = gelu_as(acc);
    }
    float h2[16];
    #pragma unroll
    for (int j = 0; j < 16; ++j) {
        float acc = b2[j];
        #pragma unroll
        for (int k = 0; k < 16; ++k) acc = fmaf(W2[j * 16 + k], h1[k], acc);
        h2[j] = gelu_as(acc);
    }
    float h3[16];
    #pragma unroll
    for (int j = 0; j < 16; ++j) {
        float acc = b3[j];
        #pragma unroll
        for (int k = 0; k < 16; ++k) acc = fmaf(W3[j * 16 + k], h2[k], acc);
        h3[j] = gelu_as(acc);
    }
    float* op = out + (size_t)i * 3;
    #pragma unroll
    for (int c = 0; c < 3; ++c) {
        float acc = bh[c];
        #pragma unroll
        for (int k = 0; k < 16; ++k) acc = fmaf(Wh[c * 16 + k], h3[k], acc);
        __builtin_nontemporal_store(acc, op + c);
    }
}

extern "C" void kernel_launch(void* const* d_in, const int* in_sizes, int n_in,
                              void* d_out, int out_size, void* d_ws, size_t ws_size,
                              hipStream_t stream) {
    const float* x  = (const float*)d_in[0];
    const float* fm = (const float*)d_in[1];
    const float* W1 = (const float*)d_in[2];
    const float* b1 = (const float*)d_in[3];
    const float* W2 = (const float*)d_in[4];
    const float* b2 = (const float*)d_in[5];
    const float* W3 = (const float*)d_in[6];
    const float* b3 = (const float*)d_in[7];
    const float* Wh = (const float*)d_in[8];
    const float* bh = (const float*)d_in[9];
    float* out = (float*)d_out;

    int B  = in_sizes[0] / 3;
    int HW = in_sizes[1] / 4;
    int H = 1;
    while ((long long)(H + 1) * (H + 1) <= (long long)HW) ++H;  // integer sqrt
    int W = HW / H;

    size_t repack_bytes = (size_t)HW * sizeof(float4);
    size_t table_bytes  = (size_t)GT_N * sizeof(float2);
    size_t wpk_bytes    = (size_t)NPAIR * sizeof(unsigned);

    int blocks_fast = (B + 256 * PPT - 1) / (256 * PPT);
    int blocks_leg  = (B + 255) / 256;

    if (ws_size >= repack_bytes + table_bytes + wpk_bytes) {
        float4* fmr  = (float4*)d_ws;
        float2* gtab = (float2*)((char*)d_ws + repack_bytes);
        unsigned* wp = (unsigned*)((char*)d_ws + repack_bytes + table_bytes);
        repack_fm_kernel<<<(HW + 255) / 256, 256, 0, stream>>>(fm, fmr, HW);
        build_gelu_table_kernel<<<GT_N / 256, 256, 0, stream>>>(gtab);
        pack_weights_kernel<<<2, 256, 0, stream>>>(W2, W3, Wh, wp);
        fused_mlp_fast_kernel<true><<<blocks_fast, 256, 0, stream>>>(
            x, fm, fmr, gtab, (const f16x2*)wp, W1, b1, b2, b3, bh, out, B, H, W);
    } else if (ws_size >= table_bytes + wpk_bytes) {
        float2* gtab = (float2*)d_ws;
        unsigned* wp = (unsigned*)((char*)d_ws + table_bytes);
        build_gelu_table_kernel<<<GT_N / 256, 256, 0, stream>>>(gtab);
        pack_weights_kernel<<<2, 256, 0, stream>>>(W2, W3, Wh, wp);
        fused_mlp_fast_kernel<false><<<blocks_fast, 256, 0, stream>>>(
            x, fm, nullptr, gtab, (const f16x2*)wp, W1, b1, b2, b3, bh, out, B, H, W);
    } else if (ws_size >= repack_bytes) {
        float4* fmr = (float4*)d_ws;
        repack_fm_kernel<<<(HW + 255) / 256, 256, 0, stream>>>(fm, fmr, HW);
        fused_mlp_kernel<true><<<blocks_leg, 256, 0, stream>>>(
            x, fm, fmr, W1, b1, W2, b2, W3, b3, Wh, bh, out, B, H, W);
    } else {
        fused_mlp_kernel<false><<<blocks_leg, 256, 0, stream>>>(
            x, fm, nullptr, W1, b1, W2, b2, W3, b3, Wh, bh, out, B, H, W);
    }
}

// Round 11
// 156.480 us; speedup vs baseline: 1.0372x; 1.0372x over previous
//
#include <hip/hip_runtime.h>
#include <math.h>

typedef _Float16 f16x2 __attribute__((ext_vector_type(2)));

#define GT_N 1024
#define NPAIR 280                // 128 (W2) + 128 (W3) + 24 (Wh) f16x2 pairs

// ---------------- featuremap repack: (4,H,W) -> (H,W,4) ----------------
__global__ void repack_fm_kernel(const float* __restrict__ fm,
                                 float4* __restrict__ out, int HW) {
    int idx = blockIdx.x * blockDim.x + threadIdx.x;
    if (idx >= HW) return;
    float4 v;
    v.x = fm[idx];
    v.y = fm[HW + idx];
    v.z = fm[2 * HW + idx];
    v.w = fm[3 * HW + idx];
    out[idx] = v;
}

// ------- GELU slope/intercept table: g(v) ~= s[i]*v + c[i], 1024 buckets on [-5,5] -------
// Built in f64. Out-of-range v self-handles: bucket 0 line ~ 0*v+0, bucket 1023
// line ~ 1.0*v - 1e-6, so the UNCLAMPED v extrapolates correctly (no select).
__global__ void build_gelu_table_kernel(float2* __restrict__ tbl) {
    int i = blockIdx.x * blockDim.x + threadIdx.x;
    if (i >= GT_N) return;
    double d  = 10.0 / 1023.0;
    double v0 = -5.0 + (double)i * d;
    double v1 = v0 + d;
    double g0 = 0.5 * v0 * (1.0 + erf(v0 * 0.70710678118654752440));
    double g1 = 0.5 * v1 * (1.0 + erf(v1 * 0.70710678118654752440));
    double s  = (g1 - g0) / d;
    double c  = g0 - s * v0;
    float2 e; e.x = (float)s; e.y = (float)c;
    tbl[i] = e;
}

// ---------------- pack W2/W3/Wh rows into f16 pairs (RNE) ----------------
__global__ void pack_weights_kernel(const float* __restrict__ W2,
                                    const float* __restrict__ W3,
                                    const float* __restrict__ Wh,
                                    unsigned* __restrict__ wp) {
    int t = blockIdx.x * blockDim.x + threadIdx.x;
    if (t >= NPAIR) return;
    float a, b;
    if (t < 128)      {              a = W2[2 * t];  b = W2[2 * t + 1]; }
    else if (t < 256) { int u = t - 128; a = W3[2 * u]; b = W3[2 * u + 1]; }
    else              { int u = t - 256; a = Wh[2 * u]; b = Wh[2 * u + 1]; }
    union { f16x2 h; unsigned u; } cv;
    cv.h.x = (_Float16)a; cv.h.y = (_Float16)b;
    wp[t] = cv.u;
}

// Fallback exact GELU (A&S 7.1.26 erfc), branchless — only for the no-ws path.
__device__ __forceinline__ float gelu_as(float v) {
    float z = fabsf(v) * 0.70710678118654752440f;
    float t = __builtin_amdgcn_rcpf(fmaf(0.3275911f, z, 1.0f));
    float e = __expf(-z * z);
    float p = fmaf(1.061405429f, t, -1.453152027f);
    p = fmaf(p, t, 1.421413741f);
    p = fmaf(p, t, -0.284496736f);
    p = fmaf(p, t, 0.254829592f);
    p = p * t;
    float he = 0.5f * p * e;
    float phi = (v >= 0.0f) ? (1.0f - he) : he;
    return v * phi;
}

// 5 VALU + 1 LDS read: med3, fma(index), cvt_i32, ds_read_b64(addr lshl), fma(eval)
__device__ __forceinline__ float gelu_lin(float v, const float2* __restrict__ gt) {
    float u = __builtin_amdgcn_fmed3f(v, -5.0f, 5.0f);
    float t = fmaf(u, 102.3f, 511.5f);      // [-5,5] -> [0,1023]
    int idx = (int)t;                       // trunc; safe by construction
    float2 sc = gt[idx];
    return fmaf(v, sc.x, sc.y);             // unclamped v: edge lines extrapolate
}

__device__ __forceinline__ f16x2 pk(float a, float b) {   // RNE pack
    f16x2 r; r.x = (_Float16)a; r.y = (_Float16)b; return r;
}

// ---------- bilinear sample + input-feature build (shared) ----------
template <bool REPACKED>
__device__ __forceinline__ void build_inp(
    float xa, float xb, float xc,
    const float* __restrict__ fm, const float4* __restrict__ fmr,
    int H, int W, float* inp)
{
    float gx = xa * 2.0f - 1.0f;
    float gy = xb * 2.0f - 1.0f;
    float ix = ((gx + 1.0f) * (float)W - 1.0f) * 0.5f;
    float iy = ((gy + 1.0f) * (float)H - 1.0f) * 0.5f;
    ix = fminf(fmaxf(ix, 0.0f), (float)(W - 1));
    iy = fminf(fmaxf(iy, 0.0f), (float)(H - 1));
    float x0f = floorf(ix), y0f = floorf(iy);
    float wx = ix - x0f, wy = iy - y0f;
    int x0 = (int)x0f, y0 = (int)y0f;
    int x1 = x0 + 1; if (x1 > W - 1) x1 = W - 1;
    int y1 = y0 + 1; if (y1 > H - 1) y1 = H - 1;

    float4 f00, f01, f10, f11;
    if (REPACKED) {
        f00 = fmr[y0 * W + x0];
        f01 = fmr[y0 * W + x1];
        f10 = fmr[y1 * W + x0];
        f11 = fmr[y1 * W + x1];
    } else {
        int HW = H * W;
        const float* c0 = fm;
        const float* c1 = fm + HW;
        const float* c2 = fm + 2 * HW;
        const float* c3 = fm + 3 * HW;
        int i00 = y0 * W + x0, i01 = y0 * W + x1;
        int i10 = y1 * W + x0, i11 = y1 * W + x1;
        f00 = make_float4(c0[i00], c1[i00], c2[i00], c3[i00]);
        f01 = make_float4(c0[i01], c1[i01], c2[i01], c3[i01]);
        f10 = make_float4(c0[i10], c1[i10], c2[i10], c3[i10]);
        f11 = make_float4(c0[i11], c1[i11], c2[i11], c3[i11]);
    }
    float omwx = 1.0f - wx, omwy = 1.0f - wy;
    float tx = f00.x * omwx + f01.x * wx, bx = f10.x * omwx + f11.x * wx;
    float ty = f00.y * omwx + f01.y * wx, by = f10.y * omwx + f11.y * wx;
    float tz = f00.z * omwx + f01.z * wx, bz = f10.z * omwx + f11.z * wx;
    float tw = f00.w * omwx + f01.w * wx, bw = f10.w * omwx + f11.w * wx;

    inp[0] = xa;
    inp[1] = xb;
    inp[2] = xc;
    inp[3] = tx * omwy + bx * wy;
    inp[4] = ty * omwy + by * wy;
    inp[5] = tz * omwy + bz * wy;
    inp[6] = tw * omwy + bw * wy;
    inp[7] = __expf(xc) - 1.0f;
}

// ---------------- FAST kernel: PPT=1, L1 fp32, L2/L3/head via v_dot2_f32_f16 ----------------
template <bool REPACKED>
__global__ __launch_bounds__(256) void fused_mlp_fast_kernel(
    const float* __restrict__ x,
    const float* __restrict__ fm,
    const float4* __restrict__ fmr,
    const float2* __restrict__ gtab,
    const f16x2* __restrict__ wpk,   // packed: W2[0,128) W3[128,256) Wh[256,280)
    const float* __restrict__ W1, const float* __restrict__ b1,
    const float* __restrict__ b2, const float* __restrict__ b3,
    const float* __restrict__ bh,
    float* __restrict__ out, int B, int H, int W)
{
    __shared__ float2 gt[GT_N];
    {
        int t = threadIdx.x;
        #pragma unroll
        for (int k = 0; k < GT_N / 256; ++k)
            gt[t + 256 * k] = gtab[t + 256 * k];
        __syncthreads();
    }

    int i = blockIdx.x * blockDim.x + threadIdx.x;
    if (i >= B) return;

    const float* xp = x + (size_t)i * 3;
    float xa = __builtin_nontemporal_load(xp + 0);
    float xb = __builtin_nontemporal_load(xp + 1);
    float xc = __builtin_nontemporal_load(xp + 2);

    float inp[8];
    build_inp<REPACKED>(xa, xb, xc, fm, fmr, H, W, inp);

    // ---- layer 1: 8 -> 16, fp32 FMA (weights scalarized), gelu -> f16 pairs ----
    f16x2 hp[8];
    #pragma unroll
    for (int e = 0; e < 8; ++e) {
        float a0 = b1[2 * e], a1 = b1[2 * e + 1];
        #pragma unroll
        for (int k = 0; k < 8; ++k) {
            a0 = fmaf(W1[(2 * e) * 8 + k], inp[k], a0);
            a1 = fmaf(W1[(2 * e + 1) * 8 + k], inp[k], a1);
        }
        hp[e] = pk(gelu_lin(a0, gt), gelu_lin(a1, gt));
    }

    // ---- layer 2: 16 -> 16 via dot2 ----
    f16x2 hq[8];
    #pragma unroll
    for (int e = 0; e < 8; ++e) {
        float a0 = b2[2 * e], a1 = b2[2 * e + 1];
        #pragma unroll
        for (int k = 0; k < 8; ++k) {
            a0 = __builtin_amdgcn_fdot2(hp[k], wpk[(2 * e) * 8 + k], a0, false);
            a1 = __builtin_amdgcn_fdot2(hp[k], wpk[(2 * e + 1) * 8 + k], a1, false);
        }
        hq[e] = pk(gelu_lin(a0, gt), gelu_lin(a1, gt));
    }

    // ---- layer 3: 16 -> 16 via dot2 ----
    #pragma unroll
    for (int e = 0; e < 8; ++e) {
        float a0 = b3[2 * e], a1 = b3[2 * e + 1];
        #pragma unroll
        for (int k = 0; k < 8; ++k) {
            a0 = __builtin_amdgcn_fdot2(hq[k], wpk[128 + (2 * e) * 8 + k], a0, false);
            a1 = __builtin_amdgcn_fdot2(hq[k], wpk[128 + (2 * e + 1) * 8 + k], a1, false);
        }
        hp[e] = pk(gelu_lin(a0, gt), gelu_lin(a1, gt));
    }

    // ---- head: 16 -> 3 via dot2 + store ----
    float o0 = bh[0], o1 = bh[1], o2 = bh[2];
    #pragma unroll
    for (int k = 0; k < 8; ++k) {
        o0 = __builtin_amdgcn_fdot2(hp[k], wpk[256 + 0 * 8 + k], o0, false);
        o1 = __builtin_amdgcn_fdot2(hp[k], wpk[256 + 1 * 8 + k], o1, false);
        o2 = __builtin_amdgcn_fdot2(hp[k], wpk[256 + 2 * 8 + k], o2, false);
    }
    float* op = out + (size_t)i * 3;
    __builtin_nontemporal_store(o0, op + 0);
    __builtin_nontemporal_store(o1, op + 1);
    __builtin_nontemporal_store(o2, op + 2);
}

// ---------------- legacy fp32 kernel (fallback if ws too small) ----------------
template <bool REPACKED>
__global__ __launch_bounds__(256) void fused_mlp_kernel(
    const float* __restrict__ x,
    const float* __restrict__ fm,
    const float4* __restrict__ fmr,
    const float* __restrict__ W1, const float* __restrict__ b1,
    const float* __restrict__ W2, const float* __restrict__ b2,
    const float* __restrict__ W3, const float* __restrict__ b3,
    const float* __restrict__ Wh, const float* __restrict__ bh,
    float* __restrict__ out, int B, int H, int W)
{
    int i = blockIdx.x * blockDim.x + threadIdx.x;
    if (i >= B) return;

    const float* xp = x + (size_t)i * 3;
    float xa = __builtin_nontemporal_load(xp + 0);
    float xb = __builtin_nontemporal_load(xp + 1);
    float xc = __builtin_nontemporal_load(xp + 2);

    float inp[8];
    build_inp<REPACKED>(xa, xb, xc, fm, fmr, H, W, inp);

    float h1[16];
    #pragma unroll
    for (int j = 0; j < 16; ++j) {
        float acc = b1[j];
        #pragma unroll
        for (int k = 0; k < 8; ++k) acc = fmaf(W1[j * 8 + k], inp[k], acc);
        h1[j] = gelu_as(acc);
    }
    float h2[16];
    #pragma unroll
    for (int j = 0; j < 16; ++j) {
        float acc = b2[j];
        #pragma unroll
        for (int k = 0; k < 16; ++k) acc = fmaf(W2[j * 16 + k], h1[k], acc);
        h2[j] = gelu_as(acc);
    }
    float h3[16];
    #pragma unroll
    for (int j = 0; j < 16; ++j) {
        float acc = b3[j];
        #pragma unroll
        for (int k = 0; k < 16; ++k) acc = fmaf(W3[j * 16 + k], h2[k], acc);
        h3[j] = gelu_as(acc);
    }
    float* op = out + (size_t)i * 3;
    #pragma unroll
    for (int c = 0; c < 3; ++c) {
        float acc = bh[c];
        #pragma unroll
        for (int k = 0; k < 16; ++k) acc = fmaf(Wh[c * 16 + k], h3[k], acc);
        __builtin_nontemporal_store(acc, op + c);
    }
}

extern "C" void kernel_launch(void* const* d_in, const int* in_sizes, int n_in,
                              void* d_out, int out_size, void* d_ws, size_t ws_size,
                              hipStream_t stream) {
    const float* x  = (const float*)d_in[0];
    const float* fm = (const float*)d_in[1];
    const float* W1 = (const float*)d_in[2];
    const float* b1 = (const float*)d_in[3];
    const float* W2 = (const float*)d_in[4];
    const float* b2 = (const float*)d_in[5];
    const float* W3 = (const float*)d_in[6];
    const float* b3 = (const float*)d_in[7];
    const float* Wh = (const float*)d_in[8];
    const float* bh = (const float*)d_in[9];
    float* out = (float*)d_out;

    int B  = in_sizes[0] / 3;
    int HW = in_sizes[1] / 4;
    int H = 1;
    while ((long long)(H + 1) * (H + 1) <= (long long)HW) ++H;  // integer sqrt
    int W = HW / H;

    size_t repack_bytes = (size_t)HW * sizeof(float4);
    size_t table_bytes  = (size_t)GT_N * sizeof(float2);
    size_t wpk_bytes    = (size_t)NPAIR * sizeof(unsigned);

    int blocks = (B + 255) / 256;

    if (ws_size >= repack_bytes + table_bytes + wpk_bytes) {
        float4* fmr  = (float4*)d_ws;
        float2* gtab = (float2*)((char*)d_ws + repack_bytes);
        unsigned* wp = (unsigned*)((char*)d_ws + repack_bytes + table_bytes);
        repack_fm_kernel<<<(HW + 255) / 256, 256, 0, stream>>>(fm, fmr, HW);
        build_gelu_table_kernel<<<GT_N / 256, 256, 0, stream>>>(gtab);
        pack_weights_kernel<<<2, 256, 0, stream>>>(W2, W3, Wh, wp);
        fused_mlp_fast_kernel<true><<<blocks, 256, 0, stream>>>(
            x, fm, fmr, gtab, (const f16x2*)wp, W1, b1, b2, b3, bh, out, B, H, W);
    } else if (ws_size >= table_bytes + wpk_bytes) {
        float2* gtab = (float2*)d_ws;
        unsigned* wp = (unsigned*)((char*)d_ws + table_bytes);
        build_gelu_table_kernel<<<GT_N / 256, 256, 0, stream>>>(gtab);
        pack_weights_kernel<<<2, 256, 0, stream>>>(W2, W3, Wh, wp);
        fused_mlp_fast_kernel<false><<<blocks, 256, 0, stream>>>(
            x, fm, nullptr, gtab, (const f16x2*)wp, W1, b1, b2, b3, bh, out, B, H, W);
    } else if (ws_size >= repack_bytes) {
        float4* fmr = (float4*)d_ws;
        repack_fm_kernel<<<(HW + 255) / 256, 256, 0, stream>>>(fm, fmr, HW);
        fused_mlp_kernel<true><<<blocks, 256, 0, stream>>>(
            x, fm, fmr, W1, b1, W2, b2, W3, b3, Wh, bh, out, B, H, W);
    } else {
        fused_mlp_kernel<false><<<blocks, 256, 0, stream>>>(
            x, fm, nullptr, W1, b1, W2, b2, W3, b3, Wh, bh, out, B, H, W);
    }
}

// Round 12
// 115.284 us; speedup vs baseline: 1.4078x; 1.3573x over previous
//
#include <hip/hip_runtime.h>
#include <math.h>

typedef _Float16 f16x2 __attribute__((ext_vector_type(2)));
typedef _Float16 f16x4 __attribute__((ext_vector_type(4)));

#define GT_N 1024
#define NPAIR 280                // 128 (W2) + 128 (W3) + 24 (Wh) f16x2 pairs

// 16-B texel pair with 8-B alignment (pair base is 8-aligned, not 16-aligned)
struct __attribute__((aligned(8))) f16pair { f16x4 t0, t1; };

// ---------------- featuremap repack: (4,H,W) fp32 -> (H,W,4) f16 ----------------
__global__ void repack_fm_kernel(const float* __restrict__ fm,
                                 f16x4* __restrict__ out, int HW) {
    int idx = blockIdx.x * blockDim.x + threadIdx.x;
    if (idx >= HW) return;
    f16x4 v;
    v.x = (_Float16)fm[idx];
    v.y = (_Float16)fm[HW + idx];
    v.z = (_Float16)fm[2 * HW + idx];
    v.w = (_Float16)fm[3 * HW + idx];
    out[idx] = v;
}

// ------- GELU slope/intercept table: g(v) ~= s[i]*v + c[i], 1024 buckets on [-5,5] -------
__global__ void build_gelu_table_kernel(float2* __restrict__ tbl) {
    int i = blockIdx.x * blockDim.x + threadIdx.x;
    if (i >= GT_N) return;
    double d  = 10.0 / 1023.0;
    double v0 = -5.0 + (double)i * d;
    double v1 = v0 + d;
    double g0 = 0.5 * v0 * (1.0 + erf(v0 * 0.70710678118654752440));
    double g1 = 0.5 * v1 * (1.0 + erf(v1 * 0.70710678118654752440));
    double s  = (g1 - g0) / d;
    double c  = g0 - s * v0;
    float2 e; e.x = (float)s; e.y = (float)c;
    tbl[i] = e;
}

// ---------------- pack W2/W3/Wh rows into f16 pairs (RNE) ----------------
__global__ void pack_weights_kernel(const float* __restrict__ W2,
                                    const float* __restrict__ W3,
                                    const float* __restrict__ Wh,
                                    unsigned* __restrict__ wp) {
    int t = blockIdx.x * blockDim.x + threadIdx.x;
    if (t >= NPAIR) return;
    float a, b;
    if (t < 128)      {              a = W2[2 * t];  b = W2[2 * t + 1]; }
    else if (t < 256) { int u = t - 128; a = W3[2 * u]; b = W3[2 * u + 1]; }
    else              { int u = t - 256; a = Wh[2 * u]; b = Wh[2 * u + 1]; }
    union { f16x2 h; unsigned u; } cv;
    cv.h.x = (_Float16)a; cv.h.y = (_Float16)b;
    wp[t] = cv.u;
}

// Fallback exact GELU (A&S 7.1.26 erfc), branchless — only for the no-ws path.
__device__ __forceinline__ float gelu_as(float v) {
    float z = fabsf(v) * 0.70710678118654752440f;
    float t = __builtin_amdgcn_rcpf(fmaf(0.3275911f, z, 1.0f));
    float e = __expf(-z * z);
    float p = fmaf(1.061405429f, t, -1.453152027f);
    p = fmaf(p, t, 1.421413741f);
    p = fmaf(p, t, -0.284496736f);
    p = fmaf(p, t, 0.254829592f);
    p = p * t;
    float he = 0.5f * p * e;
    float phi = (v >= 0.0f) ? (1.0f - he) : he;
    return v * phi;
}

// 5 VALU + 1 LDS read
__device__ __forceinline__ float gelu_lin(float v, const float2* __restrict__ gt) {
    float u = __builtin_amdgcn_fmed3f(v, -5.0f, 5.0f);
    float t = fmaf(u, 102.3f, 511.5f);      // [-5,5] -> [0,1023]
    int idx = (int)t;
    float2 sc = gt[idx];
    return fmaf(v, sc.x, sc.y);             // unclamped v: edge lines extrapolate
}

__device__ __forceinline__ f16x2 pk(float a, float b) {   // RNE pack
    f16x2 r; r.x = (_Float16)a; r.y = (_Float16)b; return r;
}

// ---------- bilinear sample from f16x4 (H,W,4) map: 2x 16-B pair loads ----------
__device__ __forceinline__ void build_inp_h(
    float xa, float xb, float xc,
    const f16x4* __restrict__ fmh,
    int H, int W, float* inp)
{
    float gx = xa * 2.0f - 1.0f;
    float gy = xb * 2.0f - 1.0f;
    float ix = ((gx + 1.0f) * (float)W - 1.0f) * 0.5f;
    float iy = ((gy + 1.0f) * (float)H - 1.0f) * 0.5f;
    ix = fminf(fmaxf(ix, 0.0f), (float)(W - 1));
    iy = fminf(fmaxf(iy, 0.0f), (float)(H - 1));
    float x0f = floorf(ix), y0f = floorf(iy);
    float wx = ix - x0f, wy = iy - y0f;
    int x0 = (int)x0f, y0 = (int)y0f;
    int y1 = y0 + 1; if (y1 > H - 1) y1 = H - 1;
    int xb_ = x0 > W - 2 ? W - 2 : x0;      // pair base; if clamped, wx==0 exactly
    bool selx = (x0 != xb_);

    const f16pair* pt = (const f16pair*)(fmh + ((size_t)y0 * W + xb_));
    const f16pair* pb = (const f16pair*)(fmh + ((size_t)y1 * W + xb_));
    f16pair rt = *pt;
    f16pair rb = *pb;

    f16x4 f00 = selx ? rt.t1 : rt.t0;
    f16x4 f01 = rt.t1;
    f16x4 f10 = selx ? rb.t1 : rb.t0;
    f16x4 f11 = rb.t1;

    _Float16 wxh = (_Float16)wx;
    _Float16 wyh = (_Float16)wy;
    f16x4 wxv = {wxh, wxh, wxh, wxh};
    f16x4 wyv = {wyh, wyh, wyh, wyh};

    f16x4 top = (f01 - f00) * wxv + f00;    // v_pk_* packed math
    f16x4 bot = (f11 - f10) * wxv + f10;
    f16x4 res = (bot - top) * wyv + top;

    inp[0] = xa;
    inp[1] = xb;
    inp[2] = xc;
    inp[3] = (float)res.x;
    inp[4] = (float)res.y;
    inp[5] = (float)res.z;
    inp[6] = (float)res.w;
    inp[7] = __expf(xc) - 1.0f;
}

// ---------- legacy fp32 bilinear (fallback path only) ----------
__device__ __forceinline__ void build_inp_f32(
    float xa, float xb, float xc,
    const float* __restrict__ fm,
    int H, int W, float* inp)
{
    float gx = xa * 2.0f - 1.0f;
    float gy = xb * 2.0f - 1.0f;
    float ix = ((gx + 1.0f) * (float)W - 1.0f) * 0.5f;
    float iy = ((gy + 1.0f) * (float)H - 1.0f) * 0.5f;
    ix = fminf(fmaxf(ix, 0.0f), (float)(W - 1));
    iy = fminf(fmaxf(iy, 0.0f), (float)(H - 1));
    float x0f = floorf(ix), y0f = floorf(iy);
    float wx = ix - x0f, wy = iy - y0f;
    int x0 = (int)x0f, y0 = (int)y0f;
    int x1 = x0 + 1; if (x1 > W - 1) x1 = W - 1;
    int y1 = y0 + 1; if (y1 > H - 1) y1 = H - 1;

    int HW = H * W;
    const float* c0 = fm;
    const float* c1 = fm + HW;
    const float* c2 = fm + 2 * HW;
    const float* c3 = fm + 3 * HW;
    int i00 = y0 * W + x0, i01 = y0 * W + x1;
    int i10 = y1 * W + x0, i11 = y1 * W + x1;
    float4 f00 = make_float4(c0[i00], c1[i00], c2[i00], c3[i00]);
    float4 f01 = make_float4(c0[i01], c1[i01], c2[i01], c3[i01]);
    float4 f10 = make_float4(c0[i10], c1[i10], c2[i10], c3[i10]);
    float4 f11 = make_float4(c0[i11], c1[i11], c2[i11], c3[i11]);

    float omwx = 1.0f - wx, omwy = 1.0f - wy;
    float tx = f00.x * omwx + f01.x * wx, bx = f10.x * omwx + f11.x * wx;
    float ty = f00.y * omwx + f01.y * wx, by = f10.y * omwx + f11.y * wx;
    float tz = f00.z * omwx + f01.z * wx, bz = f10.z * omwx + f11.z * wx;
    float tw = f00.w * omwx + f01.w * wx, bw = f10.w * omwx + f11.w * wx;

    inp[0] = xa;
    inp[1] = xb;
    inp[2] = xc;
    inp[3] = tx * omwy + bx * wy;
    inp[4] = ty * omwy + by * wy;
    inp[5] = tz * omwy + bz * wy;
    inp[6] = tw * omwy + bw * wy;
    inp[7] = __expf(xc) - 1.0f;
}

// ---------------- FAST kernel: PPT=1, f16 map, L1 fp32, L2/L3/head via v_dot2_f32_f16 ----------------
__global__ __launch_bounds__(256) void fused_mlp_fast_kernel(
    const float* __restrict__ x,
    const f16x4* __restrict__ fmh,
    const float2* __restrict__ gtab,
    const f16x2* __restrict__ wpk,   // packed: W2[0,128) W3[128,256) Wh[256,280)
    const float* __restrict__ W1, const float* __restrict__ b1,
    const float* __restrict__ b2, const float* __restrict__ b3,
    const float* __restrict__ bh,
    float* __restrict__ out, int B, int H, int W)
{
    __shared__ float2 gt[GT_N];
    {
        int t = threadIdx.x;
        #pragma unroll
        for (int k = 0; k < GT_N / 256; ++k)
            gt[t + 256 * k] = gtab[t + 256 * k];
        __syncthreads();
    }

    int i = blockIdx.x * blockDim.x + threadIdx.x;
    if (i >= B) return;

    const float* xp = x + (size_t)i * 3;
    float xa = __builtin_nontemporal_load(xp + 0);
    float xb = __builtin_nontemporal_load(xp + 1);
    float xc = __builtin_nontemporal_load(xp + 2);

    float inp[8];
    build_inp_h(xa, xb, xc, fmh, H, W, inp);

    // ---- layer 1: 8 -> 16, fp32 FMA (weights scalarized), gelu -> f16 pairs ----
    f16x2 hp[8];
    #pragma unroll
    for (int e = 0; e < 8; ++e) {
        float a0 = b1[2 * e], a1 = b1[2 * e + 1];
        #pragma unroll
        for (int k = 0; k < 8; ++k) {
            a0 = fmaf(W1[(2 * e) * 8 + k], inp[k], a0);
            a1 = fmaf(W1[(2 * e + 1) * 8 + k], inp[k], a1);
        }
        hp[e] = pk(gelu_lin(a0, gt), gelu_lin(a1, gt));
    }

    // ---- layer 2: 16 -> 16 via dot2 ----
    f16x2 hq[8];
    #pragma unroll
    for (int e = 0; e < 8; ++e) {
        float a0 = b2[2 * e], a1 = b2[2 * e + 1];
        #pragma unroll
        for (int k = 0; k < 8; ++k) {
            a0 = __builtin_amdgcn_fdot2(hp[k], wpk[(2 * e) * 8 + k], a0, false);
            a1 = __builtin_amdgcn_fdot2(hp[k], wpk[(2 * e + 1) * 8 + k], a1, false);
        }
        hq[e] = pk(gelu_lin(a0, gt), gelu_lin(a1, gt));
    }

    // ---- layer 3: 16 -> 16 via dot2 ----
    #pragma unroll
    for (int e = 0; e < 8; ++e) {
        float a0 = b3[2 * e], a1 = b3[2 * e + 1];
        #pragma unroll
        for (int k = 0; k < 8; ++k) {
            a0 = __builtin_amdgcn_fdot2(hq[k], wpk[128 + (2 * e) * 8 + k], a0, false);
            a1 = __builtin_amdgcn_fdot2(hq[k], wpk[128 + (2 * e + 1) * 8 + k], a1, false);
        }
        hp[e] = pk(gelu_lin(a0, gt), gelu_lin(a1, gt));
    }

    // ---- head: 16 -> 3 via dot2 + store ----
    float o0 = bh[0], o1 = bh[1], o2 = bh[2];
    #pragma unroll
    for (int k = 0; k < 8; ++k) {
        o0 = __builtin_amdgcn_fdot2(hp[k], wpk[256 + 0 * 8 + k], o0, false);
        o1 = __builtin_amdgcn_fdot2(hp[k], wpk[256 + 1 * 8 + k], o1, false);
        o2 = __builtin_amdgcn_fdot2(hp[k], wpk[256 + 2 * 8 + k], o2, false);
    }
    float* op = out + (size_t)i * 3;
    __builtin_nontemporal_store(o0, op + 0);
    __builtin_nontemporal_store(o1, op + 1);
    __builtin_nontemporal_store(o2, op + 2);
}

// ---------------- legacy fp32 kernel (fallback if ws too small) ----------------
__global__ __launch_bounds__(256) void fused_mlp_kernel(
    const float* __restrict__ x,
    const float* __restrict__ fm,
    const float* __restrict__ W1, const float* __restrict__ b1,
    const float* __restrict__ W2, const float* __restrict__ b2,
    const float* __restrict__ W3, const float* __restrict__ b3,
    const float* __restrict__ Wh, const float* __restrict__ bh,
    float* __restrict__ out, int B, int H, int W)
{
    int i = blockIdx.x * blockDim.x + threadIdx.x;
    if (i >= B) return;

    const float* xp = x + (size_t)i * 3;
    float xa = __builtin_nontemporal_load(xp + 0);
    float xb = __builtin_nontemporal_load(xp + 1);
    float xc = __builtin_nontemporal_load(xp + 2);

    float inp[8];
    build_inp_f32(xa, xb, xc, fm, H, W, inp);

    float h1[16];
    #pragma unroll
    for (int j = 0; j < 16; ++j) {
        float acc = b1[j];
        #pragma unroll
        for (int k = 0; k < 8; ++k) acc = fmaf(W1[j * 8 + k], inp[k], acc);
        h1[j] = gelu_as(acc);
    }
    float h2[16];
    #pragma unroll
    for (int j = 0; j < 16; ++j) {
        float acc = b2[j];
        #pragma unroll
        for (int k = 0; k < 16; ++k) acc = fmaf(W2[j * 16 + k], h1[k], acc);
        h2[j] = gelu_as(acc);
    }
    float h3[16];
    #pragma unroll
    for (int j = 0; j < 16; ++j) {
        float acc = b3[j];
        #pragma unroll
        for (int k = 0; k < 16; ++k) acc = fmaf(W3[j * 16 + k], h2[k], acc);
        h3[j] = gelu_as(acc);
    }
    float* op = out + (size_t)i * 3;
    #pragma unroll
    for (int c = 0; c < 3; ++c) {
        float acc = bh[c];
        #pragma unroll
        for (int k = 0; k < 16; ++k) acc = fmaf(Wh[c * 16 + k], h3[k], acc);
        __builtin_nontemporal_store(acc, op + c);
    }
}

extern "C" void kernel_launch(void* const* d_in, const int* in_sizes, int n_in,
                              void* d_out, int out_size, void* d_ws, size_t ws_size,
                              hipStream_t stream) {
    const float* x  = (const float*)d_in[0];
    const float* fm = (const float*)d_in[1];
    const float* W1 = (const float*)d_in[2];
    const float* b1 = (const float*)d_in[3];
    const float* W2 = (const float*)d_in[4];
    const float* b2 = (const float*)d_in[5];
    const float* W3 = (const float*)d_in[6];
    const float* b3 = (const float*)d_in[7];
    const float* Wh = (const float*)d_in[8];
    const float* bh = (const float*)d_in[9];
    float* out = (float*)d_out;

    int B  = in_sizes[0] / 3;
    int HW = in_sizes[1] / 4;
    int H = 1;
    while ((long long)(H + 1) * (H + 1) <= (long long)HW) ++H;  // integer sqrt
    int W = HW / H;

    size_t repack_bytes = (size_t)HW * sizeof(f16x4);   // 8 B/texel
    size_t table_bytes  = (size_t)GT_N * sizeof(float2);
    size_t wpk_bytes    = (size_t)NPAIR * sizeof(unsigned);

    int blocks = (B + 255) / 256;

    if (ws_size >= repack_bytes + table_bytes + wpk_bytes) {
        f16x4* fmh   = (f16x4*)d_ws;
        float2* gtab = (float2*)((char*)d_ws + repack_bytes);
        unsigned* wp = (unsigned*)((char*)d_ws + repack_bytes + table_bytes);
        repack_fm_kernel<<<(HW + 255) / 256, 256, 0, stream>>>(fm, fmh, HW);
        build_gelu_table_kernel<<<GT_N / 256, 256, 0, stream>>>(gtab);
        pack_weights_kernel<<<2, 256, 0, stream>>>(W2, W3, Wh, wp);
        fused_mlp_fast_kernel<<<blocks, 256, 0, stream>>>(
            x, fmh, gtab, (const f16x2*)wp, W1, b1, b2, b3, bh, out, B, H, W);
    } else {
        fused_mlp_kernel<<<blocks, 256, 0, stream>>>(
            x, fm, W1, b1, W2, b2, W3, b3, Wh, bh, out, B, H, W);
    }
}

// Round 14
// 114.113 us; speedup vs baseline: 1.4222x; 1.0103x over previous
//
#include <hip/hip_runtime.h>
#include <math.h>

typedef _Float16 f16x2 __attribute__((ext_vector_type(2)));
typedef _Float16 f16x4 __attribute__((ext_vector_type(4)));
typedef __fp16   fp16x2 __attribute__((ext_vector_type(2)));

#define GT_N 1024
// packed f16 pairs: W1(permuted) 64 + W2 128 + W3 128 + Wh 24
#define NPAIR 344
#define OFF_W2 64
#define OFF_W3 192
#define OFF_WH 320

// 16-B texel pair with 8-B alignment
struct __attribute__((aligned(8))) f16pair { f16x4 t0, t1; };

// ---------------- featuremap repack: (4,H,W) fp32 -> (H,W,4) f16 ----------------
__global__ void repack_fm_kernel(const float* __restrict__ fm,
                                 f16x4* __restrict__ out, int HW) {
    int idx = blockIdx.x * blockDim.x + threadIdx.x;
    if (idx >= HW) return;
    f16x4 v;
    v.x = (_Float16)fm[idx];
    v.y = (_Float16)fm[HW + idx];
    v.z = (_Float16)fm[2 * HW + idx];
    v.w = (_Float16)fm[3 * HW + idx];
    out[idx] = v;
}

// ------- GELU slope/intercept table: g(v) ~= s[i]*v + c[i], 1024 buckets on [-5,5] -------
__global__ void build_gelu_table_kernel(float2* __restrict__ tbl) {
    int i = blockIdx.x * blockDim.x + threadIdx.x;
    if (i >= GT_N) return;
    double d  = 10.0 / 1023.0;
    double v0 = -5.0 + (double)i * d;
    double v1 = v0 + d;
    double g0 = 0.5 * v0 * (1.0 + erf(v0 * 0.70710678118654752440));
    double g1 = 0.5 * v1 * (1.0 + erf(v1 * 0.70710678118654752440));
    double s  = (g1 - g0) / d;
    double c  = g0 - s * v0;
    float2 e; e.x = (float)s; e.y = (float)c;
    tbl[i] = e;
}

// ---------------- pack weights into f16 pairs (RNE) ----------------
// W1 rows are PERMUTED to pair order (k0,k1)(k2,k7)(k3,k4)(k5,k6) matching the
// runtime input layout ip[] = {(xa,xb),(xc,t_embed),(f0,f1),(f2,f3)}.
__global__ void pack_weights_kernel(const float* __restrict__ W1,
                                    const float* __restrict__ W2,
                                    const float* __restrict__ W3,
                                    const float* __restrict__ Wh,
                                    unsigned* __restrict__ wp) {
    int t = blockIdx.x * blockDim.x + threadIdx.x;
    if (t >= NPAIR) return;
    float a, b;
    if (t < OFF_W2) {
        int j = t >> 2, p = t & 3;
        const float* r = W1 + j * 8;
        if (p == 0)      { a = r[0]; b = r[1]; }
        else if (p == 1) { a = r[2]; b = r[7]; }
        else if (p == 2) { a = r[3]; b = r[4]; }
        else             { a = r[5]; b = r[6]; }
    } else if (t < OFF_W3) { int u = t - OFF_W2; a = W2[2 * u]; b = W2[2 * u + 1]; }
    else if (t < OFF_WH)   { int u = t - OFF_W3; a = W3[2 * u]; b = W3[2 * u + 1]; }
    else                   { int u = t - OFF_WH; a = Wh[2 * u]; b = Wh[2 * u + 1]; }
    union { f16x2 h; unsigned u; } cv;
    cv.h.x = (_Float16)a; cv.h.y = (_Float16)b;
    wp[t] = cv.u;
}

// Fallback exact GELU (A&S 7.1.26 erfc), branchless — only for the no-ws path.
__device__ __forceinline__ float gelu_as(float v) {
    float z = fabsf(v) * 0.70710678118654752440f;
    float t = __builtin_amdgcn_rcpf(fmaf(0.3275911f, z, 1.0f));
    float e = __expf(-z * z);
    float p = fmaf(1.061405429f, t, -1.453152027f);
    p = fmaf(p, t, 1.421413741f);
    p = fmaf(p, t, -0.284496736f);
    p = fmaf(p, t, 0.254829592f);
    p = p * t;
    float he = 0.5f * p * e;
    float phi = (v >= 0.0f) ? (1.0f - he) : he;
    return v * phi;
}

// 5 VALU + 1 LDS read
__device__ __forceinline__ float gelu_lin(float v, const float2* __restrict__ gt) {
    float u = __builtin_amdgcn_fmed3f(v, -5.0f, 5.0f);
    float t = fmaf(u, 102.3f, 511.5f);      // [-5,5] -> [0,1023]
    int idx = (int)t;
    float2 sc = gt[idx];
    return fmaf(v, sc.x, sc.y);             // unclamped v: edge lines extrapolate
}

// 1-op f16 pair pack (round-toward-zero), bit-cast to our f16x2
__device__ __forceinline__ f16x2 pkz(float a, float b) {
    union { fp16x2 p; f16x2 h; } cv;
    cv.p = __builtin_amdgcn_cvt_pkrtz(a, b);
    return cv.h;
}

// ---------------- FAST kernel: PPT=1, f16 map, all layers via v_dot2_f32_f16 ----------------
__global__ __launch_bounds__(256) void fused_mlp_fast_kernel(
    const float* __restrict__ x,
    const f16x4* __restrict__ fmh,
    const float2* __restrict__ gtab,
    const f16x2* __restrict__ wpk,
    const float* __restrict__ b1,
    const float* __restrict__ b2, const float* __restrict__ b3,
    const float* __restrict__ bh,
    float* __restrict__ out, int B, int H, int W)
{
    __shared__ float2 gt[GT_N];
    {
        int t = threadIdx.x;
        #pragma unroll
        for (int k = 0; k < GT_N / 256; ++k)
            gt[t + 256 * k] = gtab[t + 256 * k];
        __syncthreads();
    }

    int i = blockIdx.x * blockDim.x + threadIdx.x;
    if (i >= B) return;

    const float* xp = x + (size_t)i * 3;
    float xa = __builtin_nontemporal_load(xp + 0);
    float xb = __builtin_nontemporal_load(xp + 1);
    float xc = __builtin_nontemporal_load(xp + 2);

    // ---- bilinear sample (f16 packed math) -> ip[2], ip[3] stay f16 ----
    f16x2 ip[4];
    {
        float gx = xa * 2.0f - 1.0f;
        float gy = xb * 2.0f - 1.0f;
        float ix = ((gx + 1.0f) * (float)W - 1.0f) * 0.5f;
        float iy = ((gy + 1.0f) * (float)H - 1.0f) * 0.5f;
        ix = fminf(fmaxf(ix, 0.0f), (float)(W - 1));
        iy = fminf(fmaxf(iy, 0.0f), (float)(H - 1));
        float x0f = floorf(ix), y0f = floorf(iy);
        float wx = ix - x0f, wy = iy - y0f;
        int x0 = (int)x0f, y0 = (int)y0f;
        int y1 = y0 + 1; if (y1 > H - 1) y1 = H - 1;
        int xb_ = x0 > W - 2 ? W - 2 : x0;      // pair base; if clamped, wx==0 exactly
        bool selx = (x0 != xb_);

        const f16pair* pt = (const f16pair*)(fmh + ((size_t)y0 * W + xb_));
        const f16pair* pb = (const f16pair*)(fmh + ((size_t)y1 * W + xb_));
        f16pair rt = *pt;
        f16pair rb = *pb;

        f16x4 f00 = selx ? rt.t1 : rt.t0;
        f16x4 f01 = rt.t1;
        f16x4 f10 = selx ? rb.t1 : rb.t0;
        f16x4 f11 = rb.t1;

        _Float16 wxh = (_Float16)wx;
        _Float16 wyh = (_Float16)wy;
        f16x4 wxv = {wxh, wxh, wxh, wxh};
        f16x4 wyv = {wyh, wyh, wyh, wyh};

        f16x4 top = (f01 - f00) * wxv + f00;
        f16x4 bot = (f11 - f10) * wxv + f10;
        f16x4 res = (bot - top) * wyv + top;

        float texp = __expf(xc) - 1.0f;
        ip[0] = pkz(xa, xb);
        ip[1] = pkz(xc, texp);
        union { f16x4 v; f16x2 h[2]; } sp; sp.v = res;
        ip[2] = sp.h[0];
        ip[3] = sp.h[1];
    }

    // ---- layer 1: 8 -> 16 via dot2 (W1 pairs permuted to ip layout) ----
    f16x2 hp[8];
    #pragma unroll
    for (int e = 0; e < 8; ++e) {
        float a0 = b1[2 * e], a1 = b1[2 * e + 1];
        #pragma unroll
        for (int k = 0; k < 4; ++k) {
            a0 = __builtin_amdgcn_fdot2(ip[k], wpk[(2 * e) * 4 + k], a0, false);
            a1 = __builtin_amdgcn_fdot2(ip[k], wpk[(2 * e + 1) * 4 + k], a1, false);
        }
        hp[e] = pkz(gelu_lin(a0, gt), gelu_lin(a1, gt));
    }

    // ---- layer 2: 16 -> 16 via dot2 ----
    f16x2 hq[8];
    #pragma unroll
    for (int e = 0; e < 8; ++e) {
        float a0 = b2[2 * e], a1 = b2[2 * e + 1];
        #pragma unroll
        for (int k = 0; k < 8; ++k) {
            a0 = __builtin_amdgcn_fdot2(hp[k], wpk[OFF_W2 + (2 * e) * 8 + k], a0, false);
            a1 = __builtin_amdgcn_fdot2(hp[k], wpk[OFF_W2 + (2 * e + 1) * 8 + k], a1, false);
        }
        hq[e] = pkz(gelu_lin(a0, gt), gelu_lin(a1, gt));
    }

    // ---- layer 3: 16 -> 16 via dot2 ----
    #pragma unroll
    for (int e = 0; e < 8; ++e) {
        float a0 = b3[2 * e], a1 = b3[2 * e + 1];
        #pragma unroll
        for (int k = 0; k < 8; ++k) {
            a0 = __builtin_amdgcn_fdot2(hq[k], wpk[OFF_W3 + (2 * e) * 8 + k], a0, false);
            a1 = __builtin_amdgcn_fdot2(hq[k], wpk[OFF_W3 + (2 * e + 1) * 8 + k], a1, false);
        }
        hp[e] = pkz(gelu_lin(a0, gt), gelu_lin(a1, gt));
    }

    // ---- head: 16 -> 3 via dot2 + store ----
    float o0 = bh[0], o1 = bh[1], o2 = bh[2];
    #pragma unroll
    for (int k = 0; k < 8; ++k) {
        o0 = __builtin_amdgcn_fdot2(hp[k], wpk[OFF_WH + 0 * 8 + k], o0, false);
        o1 = __builtin_amdgcn_fdot2(hp[k], wpk[OFF_WH + 1 * 8 + k], o1, false);
        o2 = __builtin_amdgcn_fdot2(hp[k], wpk[OFF_WH + 2 * 8 + k], o2, false);
    }
    float* op = out + (size_t)i * 3;
    __builtin_nontemporal_store(o0, op + 0);
    __builtin_nontemporal_store(o1, op + 1);
    __builtin_nontemporal_store(o2, op + 2);
}

// ---------------- legacy fp32 kernel (fallback if ws too small) ----------------
__global__ __launch_bounds__(256) void fused_mlp_kernel(
    const float* __restrict__ x,
    const float* __restrict__ fm,
    const float* __restrict__ W1, const float* __restrict__ b1,
    const float* __restrict__ W2, const float* __restrict__ b2,
    const float* __restrict__ W3, const float* __restrict__ b3,
    const float* __restrict__ Wh, const float* __restrict__ bh,
    float* __restrict__ out, int B, int H, int W)
{
    int i = blockIdx.x * blockDim.x + threadIdx.x;
    if (i >= B) return;

    const float* xp = x + (size_t)i * 3;
    float xa = xp[0], xb = xp[1], xc = xp[2];

    float inp[8];
    {
        float gx = xa * 2.0f - 1.0f;
        float gy = xb * 2.0f - 1.0f;
        float ix = ((gx + 1.0f) * (float)W - 1.0f) * 0.5f;
        float iy = ((gy + 1.0f) * (float)H - 1.0f) * 0.5f;
        ix = fminf(fmaxf(ix, 0.0f), (float)(W - 1));
        iy = fminf(fmaxf(iy, 0.0f), (float)(H - 1));
        float x0f = floorf(ix), y0f = floorf(iy);
        float wx = ix - x0f, wy = iy - y0f;
        int x0 = (int)x0f, y0 = (int)y0f;
        int x1 = x0 + 1; if (x1 > W - 1) x1 = W - 1;
        int y1 = y0 + 1; if (y1 > H - 1) y1 = H - 1;
        int HW = H * W;
        const float* c0 = fm;
        const float* c1 = fm + HW;
        const float* c2 = fm + 2 * HW;
        const float* c3 = fm + 3 * HW;
        int i00 = y0 * W + x0, i01 = y0 * W + x1;
        int i10 = y1 * W + x0, i11 = y1 * W + x1;
        float4 f00 = make_float4(c0[i00], c1[i00], c2[i00], c3[i00]);
        float4 f01 = make_float4(c0[i01], c1[i01], c2[i01], c3[i01]);
        float4 f10 = make_float4(c0[i10], c1[i10], c2[i10], c3[i10]);
        float4 f11 = make_float4(c0[i11], c1[i11], c2[i11], c3[i11]);
        float omwx = 1.0f - wx, omwy = 1.0f - wy;
        float tx = f00.x * omwx + f01.x * wx, bx = f10.x * omwx + f11.x * wx;
        float ty = f00.y * omwx + f01.y * wx, by = f10.y * omwx + f11.y * wx;
        float tz = f00.z * omwx + f01.z * wx, bz = f10.z * omwx + f11.z * wx;
        float tw = f00.w * omwx + f01.w * wx, bw = f10.w * omwx + f11.w * wx;
        inp[0] = xa; inp[1] = xb; inp[2] = xc;
        inp[3] = tx * omwy + bx * wy;
        inp[4] = ty * omwy + by * wy;
        inp[5] = tz * omwy + bz * wy;
        inp[6] = tw * omwy + bw * wy;
        inp[7] = __expf(xc) - 1.0f;
    }

    float h1[16];
    #pragma unroll
    for (int j = 0; j < 16; ++j) {
        float acc = b1[j];
        #pragma unroll
        for (int k = 0; k < 8; ++k) acc = fmaf(W1[j * 8 + k], inp[k], acc);
        h1[j] = gelu_as(acc);
    }
    float h2[16];
    #pragma unroll
    for (int j = 0; j < 16; ++j) {
        float acc = b2[j];
        #pragma unroll
        for (int k = 0; k < 16; ++k) acc = fmaf(W2[j * 16 + k], h1[k], acc);
        h2[j] = gelu_as(acc);
    }
    float h3[16];
    #pragma unroll
    for (int j = 0; j < 16; ++j) {
        float acc = b3[j];
        #pragma unroll
        for (int k = 0; k < 16; ++k) acc = fmaf(W3[j * 16 + k], h2[k], acc);
        h3[j] = gelu_as(acc);
    }
    float* op = out + (size_t)i * 3;
    #pragma unroll
    for (int c = 0; c < 3; ++c) {
        float acc = bh[c];
        #pragma unroll
        for (int k = 0; k < 16; ++k) acc = fmaf(Wh[c * 16 + k], h3[k], acc);
        op[c] = acc;
    }
}

extern "C" void kernel_launch(void* const* d_in, const int* in_sizes, int n_in,
                              void* d_out, int out_size, void* d_ws, size_t ws_size,
                              hipStream_t stream) {
    const float* x  = (const float*)d_in[0];
    const float* fm = (const float*)d_in[1];
    const float* W1 = (const float*)d_in[2];
    const float* b1 = (const float*)d_in[3];
    const float* W2 = (const float*)d_in[4];
    const float* b2 = (const float*)d_in[5];
    const float* W3 = (const float*)d_in[6];
    const float* b3 = (const float*)d_in[7];
    const float* Wh = (const float*)d_in[8];
    const float* bh = (const float*)d_in[9];
    float* out = (float*)d_out;

    int B  = in_sizes[0] / 3;
    int HW = in_sizes[1] / 4;
    int H = 1;
    while ((long long)(H + 1) * (H + 1) <= (long long)HW) ++H;  // integer sqrt
    int W = HW / H;

    size_t repack_bytes = (size_t)HW * sizeof(f16x4);   // 8 B/texel
    size_t table_bytes  = (size_t)GT_N * sizeof(float2);
    size_t wpk_bytes    = (size_t)NPAIR * sizeof(unsigned);

    int blocks = (B + 255) / 256;

    if (ws_size >= repack_bytes + table_bytes + wpk_bytes) {
        f16x4* fmh   = (f16x4*)d_ws;
        float2* gtab = (float2*)((char*)d_ws + repack_bytes);
        unsigned* wp = (unsigned*)((char*)d_ws + repack_bytes + table_bytes);
        repack_fm_kernel<<<(HW + 255) / 256, 256, 0, stream>>>(fm, fmh, HW);
        build_gelu_table_kernel<<<GT_N / 256, 256, 0, stream>>>(gtab);
        pack_weights_kernel<<<2, 256, 0, stream>>>(W1, W2, W3, Wh, wp);
        fused_mlp_fast_kernel<<<blocks, 256, 0, stream>>>(
            x, fmh, gtab, (const f16x2*)wp, b1, b2, b3, bh, out, B, H, W);
    } else {
        fused_mlp_kernel<<<blocks, 256, 0, stream>>>(
            x, fm, W1, b1, W2, b2, W3, b3, Wh, bh, out, B, H, W);
    }
}

// Round 15
// 109.941 us; speedup vs baseline: 1.4762x; 1.0379x over previous
//
#include <hip/hip_runtime.h>
#include <math.h>

typedef _Float16 f16x2 __attribute__((ext_vector_type(2)));
typedef _Float16 f16x4 __attribute__((ext_vector_type(4)));
typedef __fp16   fp16x2 __attribute__((ext_vector_type(2)));

#define GT_N 1024
// packed f16 pairs: W1(permuted) 64 + W2 128 + W3 128 + Wh 24
#define NPAIR 344
#define OFF_W2 64
#define OFF_W3 192
#define OFF_WH 320

// 16-B texel pair with 8-B alignment
struct __attribute__((aligned(8))) f16pair { f16x4 t0, t1; };

// ---------------- fused prelude: repack featuremap + GELU table + weight pack ----------------
// blocks [0, nbRepack)            : (4,H,W) fp32 -> (H,W,4) f16
// blocks [nbRepack, nbRepack+4)   : 1024-entry GELU slope/intercept table (f64 erf)
// blocks [nbRepack+4, nbRepack+6) : pack W1(permuted)/W2/W3/Wh into f16 pairs (RNE)
__global__ void prelude_kernel(const float* __restrict__ fm,
                               f16x4* __restrict__ fmh, int HW,
                               float2* __restrict__ gtab,
                               const float* __restrict__ W1,
                               const float* __restrict__ W2,
                               const float* __restrict__ W3,
                               const float* __restrict__ Wh,
                               unsigned* __restrict__ wp,
                               int nbRepack) {
    int b = blockIdx.x;
    if (b < nbRepack) {
        int idx = b * 256 + threadIdx.x;
        if (idx >= HW) return;
        f16x4 v;
        v.x = (_Float16)fm[idx];
        v.y = (_Float16)fm[HW + idx];
        v.z = (_Float16)fm[2 * HW + idx];
        v.w = (_Float16)fm[3 * HW + idx];
        fmh[idx] = v;
    } else if (b < nbRepack + 4) {
        int i = (b - nbRepack) * 256 + threadIdx.x;
        if (i >= GT_N) return;
        double d  = 10.0 / 1023.0;
        double v0 = -5.0 + (double)i * d;
        double v1 = v0 + d;
        double g0 = 0.5 * v0 * (1.0 + erf(v0 * 0.70710678118654752440));
        double g1 = 0.5 * v1 * (1.0 + erf(v1 * 0.70710678118654752440));
        double s  = (g1 - g0) / d;
        double c  = g0 - s * v0;
        float2 e; e.x = (float)s; e.y = (float)c;
        gtab[i] = e;
    } else {
        int t = (b - nbRepack - 4) * 256 + threadIdx.x;
        if (t >= NPAIR) return;
        float a2, b2_;
        if (t < OFF_W2) {
            int j = t >> 2, p = t & 3;
            const float* r = W1 + j * 8;
            if (p == 0)      { a2 = r[0]; b2_ = r[1]; }
            else if (p == 1) { a2 = r[2]; b2_ = r[7]; }
            else if (p == 2) { a2 = r[3]; b2_ = r[4]; }
            else             { a2 = r[5]; b2_ = r[6]; }
        } else if (t < OFF_W3) { int u = t - OFF_W2; a2 = W2[2 * u]; b2_ = W2[2 * u + 1]; }
        else if (t < OFF_WH)   { int u = t - OFF_W3; a2 = W3[2 * u]; b2_ = W3[2 * u + 1]; }
        else                   { int u = t - OFF_WH; a2 = Wh[2 * u]; b2_ = Wh[2 * u + 1]; }
        union { f16x2 h; unsigned u; } cv;
        cv.h.x = (_Float16)a2; cv.h.y = (_Float16)b2_;
        wp[t] = cv.u;
    }
}

// Fallback exact GELU (A&S 7.1.26 erfc), branchless — only for the no-ws path.
__device__ __forceinline__ float gelu_as(float v) {
    float z = fabsf(v) * 0.70710678118654752440f;
    float t = __builtin_amdgcn_rcpf(fmaf(0.3275911f, z, 1.0f));
    float e = __expf(-z * z);
    float p = fmaf(1.061405429f, t, -1.453152027f);
    p = fmaf(p, t, 1.421413741f);
    p = fmaf(p, t, -0.284496736f);
    p = fmaf(p, t, 0.254829592f);
    p = p * t;
    float he = 0.5f * p * e;
    float phi = (v >= 0.0f) ? (1.0f - he) : he;
    return v * phi;
}

// 5 VALU + 1 LDS read
__device__ __forceinline__ float gelu_lin(float v, const float2* __restrict__ gt) {
    float u = __builtin_amdgcn_fmed3f(v, -5.0f, 5.0f);
    float t = fmaf(u, 102.3f, 511.5f);      // [-5,5] -> [0,1023]
    int idx = (int)t;
    float2 sc = gt[idx];
    return fmaf(v, sc.x, sc.y);             // unclamped v: edge lines extrapolate
}

// 1-op f16 pair pack (round-toward-zero), bit-cast to our f16x2
__device__ __forceinline__ f16x2 pkz(float a, float b) {
    union { fp16x2 p; f16x2 h; } cv;
    cv.p = __builtin_amdgcn_cvt_pkrtz(a, b);
    return cv.h;
}

// ---------------- FAST kernel: PPT=1, f16 map, all layers via v_dot2_f32_f16 ----------------
__global__ __launch_bounds__(256) void fused_mlp_fast_kernel(
    const float* __restrict__ x,
    const f16x4* __restrict__ fmh,
    const float2* __restrict__ gtab,
    const f16x2* __restrict__ wpk,
    const float* __restrict__ b1,
    const float* __restrict__ b2, const float* __restrict__ b3,
    const float* __restrict__ bh,
    float* __restrict__ out, int B, int H, int W)
{
    __shared__ float2 gt[GT_N];
    {
        int t = threadIdx.x;
        #pragma unroll
        for (int k = 0; k < GT_N / 256; ++k)
            gt[t + 256 * k] = gtab[t + 256 * k];
        __syncthreads();
    }

    int i = blockIdx.x * blockDim.x + threadIdx.x;
    if (i >= B) return;

    const float* xp = x + (size_t)i * 3;
    float xa = __builtin_nontemporal_load(xp + 0);
    float xb = __builtin_nontemporal_load(xp + 1);
    float xc = __builtin_nontemporal_load(xp + 2);

    // ---- bilinear sample (f16 packed math) -> ip[2], ip[3] stay f16 ----
    f16x2 ip[4];
    {
        float gx = xa * 2.0f - 1.0f;
        float gy = xb * 2.0f - 1.0f;
        float ix = ((gx + 1.0f) * (float)W - 1.0f) * 0.5f;
        float iy = ((gy + 1.0f) * (float)H - 1.0f) * 0.5f;
        ix = fminf(fmaxf(ix, 0.0f), (float)(W - 1));
        iy = fminf(fmaxf(iy, 0.0f), (float)(H - 1));
        float x0f = floorf(ix), y0f = floorf(iy);
        float wx = ix - x0f, wy = iy - y0f;
        int x0 = (int)x0f, y0 = (int)y0f;
        int y1 = y0 + 1; if (y1 > H - 1) y1 = H - 1;
        int xb_ = x0 > W - 2 ? W - 2 : x0;      // pair base; if clamped, wx==0 exactly
        bool selx = (x0 != xb_);

        const f16pair* pt = (const f16pair*)(fmh + ((size_t)y0 * W + xb_));
        const f16pair* pb = (const f16pair*)(fmh + ((size_t)y1 * W + xb_));
        f16pair rt = *pt;
        f16pair rb = *pb;

        f16x4 f00 = selx ? rt.t1 : rt.t0;
        f16x4 f01 = rt.t1;
        f16x4 f10 = selx ? rb.t1 : rb.t0;
        f16x4 f11 = rb.t1;

        _Float16 wxh = (_Float16)wx;
        _Float16 wyh = (_Float16)wy;
        f16x4 wxv = {wxh, wxh, wxh, wxh};
        f16x4 wyv = {wyh, wyh, wyh, wyh};

        f16x4 top = (f01 - f00) * wxv + f00;
        f16x4 bot = (f11 - f10) * wxv + f10;
        f16x4 res = (bot - top) * wyv + top;

        float texp = __expf(xc) - 1.0f;
        ip[0] = pkz(xa, xb);
        ip[1] = pkz(xc, texp);
        union { f16x4 v; f16x2 h[2]; } sp; sp.v = res;
        ip[2] = sp.h[0];
        ip[3] = sp.h[1];
    }

    // ---- layer 1: 8 -> 16 via dot2 (W1 pairs permuted to ip layout) ----
    f16x2 hp[8];
    #pragma unroll
    for (int e = 0; e < 8; ++e) {
        float a0 = b1[2 * e], a1 = b1[2 * e + 1];
        #pragma unroll
        for (int k = 0; k < 4; ++k) {
            a0 = __builtin_amdgcn_fdot2(ip[k], wpk[(2 * e) * 4 + k], a0, false);
            a1 = __builtin_amdgcn_fdot2(ip[k], wpk[(2 * e + 1) * 4 + k], a1, false);
        }
        hp[e] = pkz(gelu_lin(a0, gt), gelu_lin(a1, gt));
    }

    // ---- layer 2: 16 -> 16 via dot2 ----
    f16x2 hq[8];
    #pragma unroll
    for (int e = 0; e < 8; ++e) {
        float a0 = b2[2 * e], a1 = b2[2 * e + 1];
        #pragma unroll
        for (int k = 0; k < 8; ++k) {
            a0 = __builtin_amdgcn_fdot2(hp[k], wpk[OFF_W2 + (2 * e) * 8 + k], a0, false);
            a1 = __builtin_amdgcn_fdot2(hp[k], wpk[OFF_W2 + (2 * e + 1) * 8 + k], a1, false);
        }
        hq[e] = pkz(gelu_lin(a0, gt), gelu_lin(a1, gt));
    }

    // ---- layer 3: 16 -> 16 via dot2 ----
    #pragma unroll
    for (int e = 0; e < 8; ++e) {
        float a0 = b3[2 * e], a1 = b3[2 * e + 1];
        #pragma unroll
        for (int k = 0; k < 8; ++k) {
            a0 = __builtin_amdgcn_fdot2(hq[k], wpk[OFF_W3 + (2 * e) * 8 + k], a0, false);
            a1 = __builtin_amdgcn_fdot2(hq[k], wpk[OFF_W3 + (2 * e + 1) * 8 + k], a1, false);
        }
        hp[e] = pkz(gelu_lin(a0, gt), gelu_lin(a1, gt));
    }

    // ---- head: 16 -> 3 via dot2 + store ----
    float o0 = bh[0], o1 = bh[1], o2 = bh[2];
    #pragma unroll
    for (int k = 0; k < 8; ++k) {
        o0 = __builtin_amdgcn_fdot2(hp[k], wpk[OFF_WH + 0 * 8 + k], o0, false);
        o1 = __builtin_amdgcn_fdot2(hp[k], wpk[OFF_WH + 1 * 8 + k], o1, false);
        o2 = __builtin_amdgcn_fdot2(hp[k], wpk[OFF_WH + 2 * 8 + k], o2, false);
    }
    float* op = out + (size_t)i * 3;
    __builtin_nontemporal_store(o0, op + 0);
    __builtin_nontemporal_store(o1, op + 1);
    __builtin_nontemporal_store(o2, op + 2);
}

// ---------------- legacy fp32 kernel (fallback if ws too small) ----------------
__global__ __launch_bounds__(256) void fused_mlp_kernel(
    const float* __restrict__ x,
    const float* __restrict__ fm,
    const float* __restrict__ W1, const float* __restrict__ b1,
    const float* __restrict__ W2, const float* __restrict__ b2,
    const float* __restrict__ W3, const float* __restrict__ b3,
    const float* __restrict__ Wh, const float* __restrict__ bh,
    float* __restrict__ out, int B, int H, int W)
{
    int i = blockIdx.x * blockDim.x + threadIdx.x;
    if (i >= B) return;

    const float* xp = x + (size_t)i * 3;
    float xa = xp[0], xb = xp[1], xc = xp[2];

    float inp[8];
    {
        float gx = xa * 2.0f - 1.0f;
        float gy = xb * 2.0f - 1.0f;
        float ix = ((gx + 1.0f) * (float)W - 1.0f) * 0.5f;
        float iy = ((gy + 1.0f) * (float)H - 1.0f) * 0.5f;
        ix = fminf(fmaxf(ix, 0.0f), (float)(W - 1));
        iy = fminf(fmaxf(iy, 0.0f), (float)(H - 1));
        float x0f = floorf(ix), y0f = floorf(iy);
        float wx = ix - x0f, wy = iy - y0f;
        int x0 = (int)x0f, y0 = (int)y0f;
        int x1 = x0 + 1; if (x1 > W - 1) x1 = W - 1;
        int y1 = y0 + 1; if (y1 > H - 1) y1 = H - 1;
        int HW = H * W;
        const float* c0 = fm;
        const float* c1 = fm + HW;
        const float* c2 = fm + 2 * HW;
        const float* c3 = fm + 3 * HW;
        int i00 = y0 * W + x0, i01 = y0 * W + x1;
        int i10 = y1 * W + x0, i11 = y1 * W + x1;
        float4 f00 = make_float4(c0[i00], c1[i00], c2[i00], c3[i00]);
        float4 f01 = make_float4(c0[i01], c1[i01], c2[i01], c3[i01]);
        float4 f10 = make_float4(c0[i10], c1[i10], c2[i10], c3[i10]);
        float4 f11 = make_float4(c0[i11], c1[i11], c2[i11], c3[i11]);
        float omwx = 1.0f - wx, omwy = 1.0f - wy;
        float tx = f00.x * omwx + f01.x * wx, bx = f10.x * omwx + f11.x * wx;
        float ty = f00.y * omwx + f01.y * wx, by = f10.y * omwx + f11.y * wx;
        float tz = f00.z * omwx + f01.z * wx, bz = f10.z * omwx + f11.z * wx;
        float tw = f00.w * omwx + f01.w * wx, bw = f10.w * omwx + f11.w * wx;
        inp[0] = xa; inp[1] = xb; inp[2] = xc;
        inp[3] = tx * omwy + bx * wy;
        inp[4] = ty * omwy + by * wy;
        inp[5] = tz * omwy + bz * wy;
        inp[6] = tw * omwy + bw * wy;
        inp[7] = __expf(xc) - 1.0f;
    }

    float h1[16];
    #pragma unroll
    for (int j = 0; j < 16; ++j) {
        float acc = b1[j];
        #pragma unroll
        for (int k = 0; k < 8; ++k) acc = fmaf(W1[j * 8 + k], inp[k], acc);
        h1[j] = gelu_as(acc);
    }
    float h2[16];
    #pragma unroll
    for (int j = 0; j < 16; ++j) {
        float acc = b2[j];
        #pragma unroll
        for (int k = 0; k < 16; ++k) acc = fmaf(W2[j * 16 + k], h1[k], acc);
        h2[j] = gelu_as(acc);
    }
    float h3[16];
    #pragma unroll
    for (int j = 0; j < 16; ++j) {
        float acc = b3[j];
        #pragma unroll
        for (int k = 0; k < 16; ++k) acc = fmaf(W3[j * 16 + k], h2[k], acc);
        h3[j] = gelu_as(acc);
    }
    float* op = out + (size_t)i * 3;
    #pragma unroll
    for (int c = 0; c < 3; ++c) {
        float acc = bh[c];
        #pragma unroll
        for (int k = 0; k < 16; ++k) acc = fmaf(Wh[c * 16 + k], h3[k], acc);
        op[c] = acc;
    }
}

extern "C" void kernel_launch(void* const* d_in, const int* in_sizes, int n_in,
                              void* d_out, int out_size, void* d_ws, size_t ws_size,
                              hipStream_t stream) {
    const float* x  = (const float*)d_in[0];
    const float* fm = (const float*)d_in[1];
    const float* W1 = (const float*)d_in[2];
    const float* b1 = (const float*)d_in[3];
    const float* W2 = (const float*)d_in[4];
    const float* b2 = (const float*)d_in[5];
    const float* W3 = (const float*)d_in[6];
    const float* b3 = (const float*)d_in[7];
    const float* Wh = (const float*)d_in[8];
    const float* bh = (const float*)d_in[9];
    float* out = (float*)d_out;

    int B  = in_sizes[0] / 3;
    int HW = in_sizes[1] / 4;
    int H = 1;
    while ((long long)(H + 1) * (H + 1) <= (long long)HW) ++H;  // integer sqrt
    int W = HW / H;

    size_t repack_bytes = (size_t)HW * sizeof(f16x4);   // 8 B/texel
    size_t table_bytes  = (size_t)GT_N * sizeof(float2);
    size_t wpk_bytes    = (size_t)NPAIR * sizeof(unsigned);

    int blocks = (B + 255) / 256;

    if (ws_size >= repack_bytes + table_bytes + wpk_bytes) {
        f16x4* fmh   = (f16x4*)d_ws;
        float2* gtab = (float2*)((char*)d_ws + repack_bytes);
        unsigned* wp = (unsigned*)((char*)d_ws + repack_bytes + table_bytes);
        int nbRepack = (HW + 255) / 256;
        // fused prelude: repack + table + weight pack in ONE launch
        prelude_kernel<<<nbRepack + 4 + 2, 256, 0, stream>>>(
            fm, fmh, HW, gtab, W1, W2, W3, Wh, wp, nbRepack);
        fused_mlp_fast_kernel<<<blocks, 256, 0, stream>>>(
            x, fmh, gtab, (const f16x2*)wp, b1, b2, b3, bh, out, B, H, W);
    } else {
        fused_mlp_kernel<<<blocks, 256, 0, stream>>>(
            x, fm, W1, b1, W2, b2, W3, b3, Wh, bh, out, B, H, W);
    }
}